// Round 5
// baseline (2492.629 us; speedup 1.0000x reference)
//
#include <hip/hip_runtime.h>
#include <hip/hip_bf16.h>

#define BB  2048
#define TT  128
#define DD  128
#define HH1 128
#define GG1 512
#define HH2 64
#define GG2 256
#define OO  64

typedef __attribute__((ext_vector_type(8))) short  short8;
typedef __attribute__((ext_vector_type(4))) float  floatx4;

// Pin a value into VGPRs: opaque asm makes rematerializing the load illegal.
#define PIN(x) asm volatile("" : "+v"(x))

// ws byte offsets
#define OFF_WHH1 0            // bf16 [512][128]  (exp2-prescaled)
#define OFF_WIH1 131072       // bf16 [512][128]  (exp2-prescaled)
#define OFF_WIH2 262144       // bf16 [256][128]  (exp2-prescaled)
#define OFF_WHH2 327680       // bf16 [256][64]   (exp2-prescaled)
#define OFF_B1   360448       // f32 [512]  (b_ih1+b_hh1)*scale
#define OFF_B2   362496       // f32 [256]  (b_ih2+b_hh2)*scale
#define OFF_FLAGS 363520      // i32 [256]  producer progress flags (zeroed by k_prep)
#define OFF_XBF  524288       // bf16 [2048][128][128]  x cast to bf16
#define OFF_H1S  67633152     // bf16 [2048][128][128]  layer-1 hidden seq

#define NCHUNK   256          // 2048 rows / 8 rows-per-chunk

#define L2E      1.44269504088896340736f
#define TWO_L2E  2.88539008177792681472f

__device__ __forceinline__ short f2bf(float f) {
  unsigned u = __float_as_uint(f);
  unsigned r = (u + 0x7FFFu + ((u >> 16) & 1u)) >> 16;
  return (short)r;
}
__device__ __forceinline__ float exp2_f(float x) {
  float r; asm("v_exp_f32 %0, %1" : "=v"(r) : "v"(x)); return r;
}
// y is pre-scaled: y = -x*log2(e)   -> sigmoid(x)
__device__ __forceinline__ float sigm2(float y) {
  return __builtin_amdgcn_rcpf(1.0f + exp2_f(y));
}
// y is pre-scaled: y = 2x*log2(e)   -> tanh(x)
__device__ __forceinline__ float tanh2(float y) {
  return fmaf(-2.0f, __builtin_amdgcn_rcpf(1.0f + exp2_f(y)), 1.0f);
}

// Barrier that drains ONLY LDS ops (lgkmcnt). Global stores / prefetch loads
// stay in flight across it.
__device__ __forceinline__ void lds_barrier() {
  asm volatile("s_waitcnt lgkmcnt(0)" ::: "memory");
  __builtin_amdgcn_s_barrier();
  asm volatile("" ::: "memory");
}

// Consumer-side wait: relaxed device-scope polls, then acquire fence.
__device__ __forceinline__ void wait_flag(const int* flagp, int& seen, int need) {
  if (seen >= need) return;
  while ((seen = __hip_atomic_load(flagp, __ATOMIC_RELAXED,
                                   __HIP_MEMORY_SCOPE_AGENT)) < need) {
    __builtin_amdgcn_s_sleep(2);
  }
  __threadfence();   // acquire: invalidate caches before reading published h1s
}

// ---------------- prep: bf16 weight conversion + combined biases + flag zero ----
__global__ void k_prep(const float* __restrict__ wih1, const float* __restrict__ whh1,
                       const float* __restrict__ bih1, const float* __restrict__ bhh1,
                       const float* __restrict__ wih2, const float* __restrict__ whh2,
                       const float* __restrict__ bih2, const float* __restrict__ bhh2,
                       char* __restrict__ ws) {
  short* WHH1 = (short*)(ws + OFF_WHH1);
  short* WIH1 = (short*)(ws + OFF_WIH1);
  short* WIH2 = (short*)(ws + OFF_WIH2);
  short* WHH2 = (short*)(ws + OFF_WHH2);
  float* B1 = (float*)(ws + OFF_B1);
  float* B2 = (float*)(ws + OFF_B2);
  int* FLAGS = (int*)(ws + OFF_FLAGS);
  int idx = blockIdx.x * blockDim.x + threadIdx.x;
  int stride = gridDim.x * blockDim.x;
  const float SCI = -L2E, SCG = TWO_L2E;
  for (int i = idx; i < GG1 * DD; i += stride) {
    int g = (i >> 7) >> 7;
    float s = (g == 2) ? SCG : SCI;
    WIH1[i] = f2bf(wih1[i] * s); WHH1[i] = f2bf(whh1[i] * s);
  }
  for (int i = idx; i < GG2 * HH1; i += stride) {
    int g = (i >> 7) >> 6; float s = (g == 2) ? SCG : SCI;
    WIH2[i] = f2bf(wih2[i] * s);
  }
  for (int i = idx; i < GG2 * HH2; i += stride) {
    int g = (i >> 6) >> 6; float s = (g == 2) ? SCG : SCI;
    WHH2[i] = f2bf(whh2[i] * s);
  }
  for (int i = idx; i < GG1; i += stride) {
    float s = ((i >> 7) == 2) ? SCG : SCI;
    B1[i] = (bih1[i] + bhh1[i]) * s;
  }
  for (int i = idx; i < GG2; i += stride) {
    float s = ((i >> 6) == 2) ? SCG : SCI;
    B2[i] = (bih2[i] + bhh2[i]) * s;
  }
  for (int i = idx; i < NCHUNK; i += stride) FLAGS[i] = 0;
}

// ---------------- xcast: x fp32 -> bf16, 8 elems/thread ----------------
__global__ __launch_bounds__(256) void k_xcast(const float* __restrict__ x,
                                               short* __restrict__ xbf) {
  size_t i = ((size_t)blockIdx.x * 256 + threadIdx.x) * 8;
  float4 a = *(const float4*)&x[i];
  float4 b = *(const float4*)&x[i + 4];
  short8 o;
  o[0] = f2bf(a.x); o[1] = f2bf(a.y); o[2] = f2bf(a.z); o[3] = f2bf(a.w);
  o[4] = f2bf(b.x); o[5] = f2bf(b.y); o[6] = f2bf(b.z); o[7] = f2bf(b.w);
  *(short8*)&xbf[i] = o;
}

// ---------------- fused: layer-1 producer + layer-2 consumer, pipelined --------
// Grid 512, block 512, __launch_bounds__(512,4) => VGPR<=128 => 2 blocks/CU =>
// ALL blocks co-resident (capacity 512 >= grid 512): no deadlock regardless of
// dispatch order. Block 2c = producer for rows c*8..c*8+7 (layer 1, publishes
// h1s + flag every 4 steps with release semantics); block 2c+1 = consumer
// (layer 2 + dense head, acquire-waits on flag before each h1 prefetch).
__global__ __launch_bounds__(512, 4) void k_fused(char* __restrict__ ws,
                                                  short* __restrict__ h1s,
                                                  const float* __restrict__ wd,
                                                  const float* __restrict__ bd,
                                                  float* __restrict__ out) {
  __shared__ __align__(16) char smem[12672];
  const int chunk = blockIdx.x >> 1;
  const int r0 = chunk * 8;
  int* flagp = (int*)(ws + OFF_FLAGS) + chunk;
  const int lane = threadIdx.x & 63;
  const int wv = threadIdx.x >> 6;          // 0..7
  const int col = lane & 15, quad = lane >> 4;

  if ((blockIdx.x & 1) == 0) {
    // ================= producer: layer 1 (R3 rec1f structure) =================
    short* hb0 = (short*)smem;              // [16*136]
    short* hb1 = (short*)smem + 16 * 136;   // [16*136]
    const short* WHH = (const short*)(ws + OFF_WHH1);
    const short* WIH = (const short*)(ws + OFF_WIH1);
    const short* XBF = (const short*)(ws + OFF_XBF);
    const float* B1 = (const float*)(ws + OFF_B1);
    const int hc = wv * 16 + col;

    short8 wh[4][4], wx[4][4];
#pragma unroll
    for (int gt = 0; gt < 4; ++gt)
#pragma unroll
      for (int kk = 0; kk < 4; ++kk) {
        wh[gt][kk] = *(const short8*)&WHH[(gt * 128 + hc) * HH1 + kk * 32 + quad * 8];
        wx[gt][kk] = *(const short8*)&WIH[(gt * 128 + hc) * DD + kk * 32 + quad * 8];
        PIN(wh[gt][kk]);
        PIN(wx[gt][kk]);
      }
    floatx4 BIASV[4];
#pragma unroll
    for (int gt = 0; gt < 4; ++gt) {
      float b = B1[gt * 128 + hc];
      BIASV[gt] = (floatx4){b, b, b, b};
      PIN(BIASV[gt]);
    }

    for (int i = threadIdx.x; i < 2 * 16 * 136; i += 512) ((short*)smem)[2 * i / 2] = 0, ((short*)smem)[i] = 0;

    const bool aload = (col < 8);
    const short* xbase = XBF + (size_t)(r0 + (col & 7)) * TT * DD;
    const short8 zz = {0, 0, 0, 0, 0, 0, 0, 0};
    short8 axA[4], axB[4];
    floatx4 accA[4], accB[4];

    // prologue: accA = bias + x_0*Wx ; axA = x_1 ; axB = 0
    {
      short8 ax0[4];
#pragma unroll
      for (int kk = 0; kk < 4; ++kk)
        ax0[kk] = aload ? *(const short8*)&xbase[kk * 32 + quad * 8] : zz;
#pragma unroll
      for (int gt = 0; gt < 4; ++gt)
        accA[gt] = __builtin_amdgcn_mfma_f32_16x16x32_bf16(ax0[0], wx[gt][0], BIASV[gt], 0, 0, 0);
#pragma unroll
      for (int kk = 1; kk < 4; ++kk)
#pragma unroll
        for (int gt = 0; gt < 4; ++gt)
          accA[gt] = __builtin_amdgcn_mfma_f32_16x16x32_bf16(ax0[kk], wx[gt][kk], accA[gt], 0, 0, 0);
    }
#pragma unroll
    for (int kk = 0; kk < 4; ++kk) {
      axA[kk] = aload ? *(const short8*)&xbase[DD + kk * 32 + quad * 8] : zz;
      axB[kk] = zz;
    }

    const int row0 = (quad & 1) * 4 + (quad >> 1) * 2;
    float c0 = 0.f, c1 = 0.f;
    __syncthreads();   // covers hbds zero-init

    auto pstep = [&](int t, short* rbuf, short* wbuf, floatx4* A, floatx4* Bn,
                     short8* axC, short8* axP) {
      const bool pub = ((t & 3) == 3);
      if (!pub && aload && t + 2 < TT) {
#pragma unroll
        for (int kk = 0; kk < 4; ++kk)
          axP[kk] = *(const short8*)&xbase[(t + 2) * DD + kk * 32 + quad * 8];
      }
      short8 ah[4];
#pragma unroll
      for (int kk = 0; kk < 4; ++kk)
        ah[kk] = *(const short8*)&rbuf[col * 136 + kk * 32 + quad * 8];
#pragma unroll
      for (int kk = 0; kk < 4; ++kk)
#pragma unroll
        for (int gt = 0; gt < 4; ++gt)
          A[gt] = __builtin_amdgcn_mfma_f32_16x16x32_bf16(ah[kk], wh[gt][kk], A[gt], 0, 0, 0);
      // pipelined input projection for t+1
#pragma unroll
      for (int gt = 0; gt < 4; ++gt)
        Bn[gt] = __builtin_amdgcn_mfma_f32_16x16x32_bf16(axC[0], wx[gt][0], BIASV[gt], 0, 0, 0);
#pragma unroll
      for (int kk = 1; kk < 4; ++kk)
#pragma unroll
        for (int gt = 0; gt < 4; ++gt)
          Bn[gt] = __builtin_amdgcn_mfma_f32_16x16x32_bf16(axC[kk], wx[gt][kk], Bn[gt], 0, 0, 0);

      float g0[4], g1[4];
#pragma unroll
      for (int gt = 0; gt < 4; ++gt) {
        float v2 = __shfl_xor(A[gt][2], 32);
        float v3 = __shfl_xor(A[gt][3], 32);
        g0[gt] = (quad < 2) ? A[gt][0] : v2;
        g1[gt] = (quad < 2) ? A[gt][1] : v3;
      }
      {
        float i0 = sigm2(g0[0]), f0 = sigm2(g0[1]), gg0 = tanh2(g0[2]), o0 = sigm2(g0[3]);
        c0 = fmaf(f0, c0, i0 * gg0);
        float hA = o0 * tanh2(c0 * TWO_L2E);
        float i1 = sigm2(g1[0]), f1 = sigm2(g1[1]), gg1 = tanh2(g1[2]), o1 = sigm2(g1[3]);
        c1 = fmaf(f1, c1, i1 * gg1);
        float hB = o1 * tanh2(c1 * TWO_L2E);
        short ha = f2bf(hA), hbv = f2bf(hB);
        wbuf[(row0)     * 136 + hc] = ha;
        wbuf[(row0 + 1) * 136 + hc] = hbv;
        h1s[((size_t)(r0 + row0)     * TT + t) * HH1 + hc] = ha;
        h1s[((size_t)(r0 + row0 + 1) * TT + t) * HH1 + hc] = hbv;
      }
      if (pub) {
        __syncthreads();             // drains vmcnt: all waves' h1s stores done
        if (threadIdx.x == 0) {
          __threadfence();           // release: write back XCD L2 to fabric
          __hip_atomic_store(flagp, t + 1, __ATOMIC_RELAXED, __HIP_MEMORY_SCOPE_AGENT);
        }
        if (aload && t + 2 < TT) {   // prefetch moved after drain
#pragma unroll
          for (int kk = 0; kk < 4; ++kk)
            axP[kk] = *(const short8*)&xbase[(t + 2) * DD + kk * 32 + quad * 8];
        }
      } else {
        lds_barrier();
      }
    };

    for (int t = 0; t < TT; t += 2) {
      pstep(t,     hb0, hb1, accA, accB, axA, axB);
      pstep(t + 1, hb1, hb0, accB, accA, axB, axA);
    }

  } else {
    // ================= consumer: layer 2 + dense head (R4 rec2f) =================
    short* hbuf = (short*)smem;                         // [16*72]
    float* gsm  = (float*)(smem + 2304);                // [8*260]
    float* h2f  = (float*)(smem + 2304 + 8320);         // [8*64]
    const short* WHH = (const short*)(ws + OFF_WHH2);
    const short* WIH = (const short*)(ws + OFF_WIH2);
    const float* B2 = (const float*)(ws + OFF_B2);
    const int n0 = wv * 32;

    short8 wh[2][2], wx[2][4];
#pragma unroll
    for (int nt = 0; nt < 2; ++nt) {
#pragma unroll
      for (int kk = 0; kk < 2; ++kk) {
        wh[nt][kk] = *(const short8*)&WHH[(n0 + nt * 16 + col) * HH2 + kk * 32 + quad * 8];
        PIN(wh[nt][kk]);
      }
#pragma unroll
      for (int kk = 0; kk < 4; ++kk) {
        wx[nt][kk] = *(const short8*)&WIH[(n0 + nt * 16 + col) * HH1 + kk * 32 + quad * 8];
        PIN(wx[nt][kk]);
      }
    }
    floatx4 BIASV[2];
#pragma unroll
    for (int nt = 0; nt < 2; ++nt) {
      float b = B2[n0 + nt * 16 + col];
      BIASV[nt] = (floatx4){b, b, b, b};
      PIN(BIASV[nt]);
    }

    for (int i = threadIdx.x; i < 16 * 72; i += 512) hbuf[i] = 0;

    const bool aload = (col < 8);
    const short* h1base = h1s + (size_t)(r0 + (col & 7)) * TT * HH1;
    const short8 zz = {0, 0, 0, 0, 0, 0, 0, 0};
    short8 axA[4], axB[4];
    floatx4 accA[2], accB[2];
    int seen = 0;

    wait_flag(flagp, seen, 2);   // h1[0], h1[1] published

    // prologue: accA = bias + h1_0*Wih2 ; axA = h1_1 ; axB = 0
    {
      short8 ax0[4];
#pragma unroll
      for (int kk = 0; kk < 4; ++kk)
        ax0[kk] = aload ? *(const short8*)&h1base[kk * 32 + quad * 8] : zz;
#pragma unroll
      for (int nt = 0; nt < 2; ++nt)
        accA[nt] = __builtin_amdgcn_mfma_f32_16x16x32_bf16(ax0[0], wx[nt][0], BIASV[nt], 0, 0, 0);
#pragma unroll
      for (int kk = 1; kk < 4; ++kk)
#pragma unroll
        for (int nt = 0; nt < 2; ++nt)
          accA[nt] = __builtin_amdgcn_mfma_f32_16x16x32_bf16(ax0[kk], wx[nt][kk], accA[nt], 0, 0, 0);
    }
#pragma unroll
    for (int kk = 0; kk < 4; ++kk) {
      axA[kk] = aload ? *(const short8*)&h1base[HH1 + kk * 32 + quad * 8] : zz;
      axB[kk] = zz;
    }

    const int j = threadIdx.x & 63;     // cell col
    const int rr = threadIdx.x >> 6;    // cell row 0..7
    float cc = 0.f;
    __syncthreads();   // covers hbuf zero-init

    auto cstep = [&](int t, floatx4* A, floatx4* Bn, short8* axC, short8* axP) {
      short8 ah[2];
#pragma unroll
      for (int kk = 0; kk < 2; ++kk)
        ah[kk] = *(const short8*)&hbuf[col * 72 + kk * 32 + quad * 8];
#pragma unroll
      for (int kk = 0; kk < 2; ++kk)
#pragma unroll
        for (int nt = 0; nt < 2; ++nt)
          A[nt] = __builtin_amdgcn_mfma_f32_16x16x32_bf16(ah[kk], wh[nt][kk], A[nt], 0, 0, 0);

      if (quad < 2) {
#pragma unroll
        for (int nt = 0; nt < 2; ++nt)
#pragma unroll
          for (int r = 0; r < 4; ++r)
            gsm[(quad * 4 + r) * 260 + n0 + nt * 16 + col] = A[nt][r];
      }

      // pipelined input projection for t+1
#pragma unroll
      for (int nt = 0; nt < 2; ++nt)
        Bn[nt] = __builtin_amdgcn_mfma_f32_16x16x32_bf16(axC[0], wx[nt][0], BIASV[nt], 0, 0, 0);
#pragma unroll
      for (int kk = 1; kk < 4; ++kk)
#pragma unroll
        for (int nt = 0; nt < 2; ++nt)
          Bn[nt] = __builtin_amdgcn_mfma_f32_16x16x32_bf16(axC[kk], wx[nt][kk], Bn[nt], 0, 0, 0);
      // gated prefetch of h1_{t+2}
      if (t + 2 < TT) {
        wait_flag(flagp, seen, t + 3);
        if (aload) {
#pragma unroll
          for (int kk = 0; kk < 4; ++kk)
            axP[kk] = *(const short8*)&h1base[(t + 2) * HH1 + kk * 32 + quad * 8];
        }
      }

      lds_barrier();    // gsm visible

      {
        float i0 = gsm[rr * 260 + j],       f0 = gsm[rr * 260 + 64 + j];
        float g0 = gsm[rr * 260 + 128 + j], o0 = gsm[rr * 260 + 192 + j];
        cc = fmaf(sigm2(f0), cc, sigm2(i0) * tanh2(g0));
        float hh = sigm2(o0) * tanh2(cc * TWO_L2E);
        hbuf[rr * 72 + j] = f2bf(hh);
        if (t == TT - 1) h2f[rr * HH2 + j] = hh;
      }
      lds_barrier();    // hbuf visible, gsm free
    };

    for (int t = 0; t < TT; t += 2) {
      cstep(t,     accA, accB, axA, axB);
      cstep(t + 1, accB, accA, axB, axA);
    }

    // dense head (fp32): 8 rows x 64 outs = 512 threads, 1 each
    {
      const int o = threadIdx.x & 63;
      const int r = threadIdx.x >> 6;
      float acc = bd[o];
      for (int k = 0; k < HH2; ++k)
        acc = fmaf(h2f[r * HH2 + k], wd[o * HH2 + k], acc);
      out[(size_t)(r0 + r) * OO + o] = fmaxf(acc, 0.f);
    }
  }
}

extern "C" void kernel_launch(void* const* d_in, const int* in_sizes, int n_in,
                              void* d_out, int out_size, void* d_ws, size_t ws_size,
                              hipStream_t stream) {
  const float* x       = (const float*)d_in[0];
  const float* w_ih1   = (const float*)d_in[1];
  const float* w_hh1   = (const float*)d_in[2];
  const float* b_ih1   = (const float*)d_in[3];
  const float* b_hh1   = (const float*)d_in[4];
  const float* w_ih2   = (const float*)d_in[5];
  const float* w_hh2   = (const float*)d_in[6];
  const float* b_ih2   = (const float*)d_in[7];
  const float* b_hh2   = (const float*)d_in[8];
  const float* w_dense = (const float*)d_in[9];
  const float* b_dense = (const float*)d_in[10];
  char* ws = (char*)d_ws;
  short* xbf = (short*)(ws + OFF_XBF);
  short* h1s = (short*)(ws + OFF_H1S);
  float* out = (float*)d_out;

  hipLaunchKernelGGL(k_prep, dim3(256), dim3(256), 0, stream,
                     w_ih1, w_hh1, b_ih1, b_hh1, w_ih2, w_hh2, b_ih2, b_hh2, ws);
  hipLaunchKernelGGL(k_xcast, dim3((BB * TT * DD) / (256 * 8)), dim3(256), 0, stream, x, xbf);
  hipLaunchKernelGGL(k_fused, dim3(2 * NCHUNK), dim3(512), 0, stream,
                     ws, h1s, w_dense, b_dense, out);
}

// Round 7
// 414.353 us; speedup vs baseline: 6.0157x; 6.0157x over previous
//
#include <hip/hip_runtime.h>
#include <hip/hip_bf16.h>

#define BB  2048
#define TT  128
#define DD  128
#define HH1 128
#define GG1 512
#define HH2 64
#define GG2 256
#define OO  64

typedef __attribute__((ext_vector_type(8))) short  short8;
typedef __attribute__((ext_vector_type(4))) float  floatx4;

// Pin a value into VGPRs: opaque asm makes rematerializing the load illegal.
#define PIN(x) asm volatile("" : "+v"(x))

// ws byte offsets
#define OFF_WHH1 0            // bf16 [512][128]  (exp2-prescaled)
#define OFF_WIH1 131072       // bf16 [512][128]  (exp2-prescaled)
#define OFF_WIH2 262144       // bf16 [256][128]  (exp2-prescaled)
#define OFF_WHH2 327680       // bf16 [256][64]   (exp2-prescaled)
#define OFF_B1   360448       // f32 [512]  (b_ih1+b_hh1)*scale
#define OFF_B2   362496       // f32 [256]  (b_ih2+b_hh2)*scale
#define OFF_XBF  524288       // bf16 [2048][128][128]  x cast to bf16
#define OFF_H1S  67633152     // bf16 [2048][128][128]  layer-1 hidden seq

#define L2E      1.44269504088896340736f
#define TWO_L2E  2.88539008177792681472f

__device__ __forceinline__ short f2bf(float f) {
  unsigned u = __float_as_uint(f);
  unsigned r = (u + 0x7FFFu + ((u >> 16) & 1u)) >> 16;
  return (short)r;
}
__device__ __forceinline__ float exp2_f(float x) {
  float r; asm("v_exp_f32 %0, %1" : "=v"(r) : "v"(x)); return r;
}
// y is pre-scaled: y = -x*log2(e)   -> sigmoid(x)
__device__ __forceinline__ float sigm2(float y) {
  return __builtin_amdgcn_rcpf(1.0f + exp2_f(y));
}
// y is pre-scaled: y = 2x*log2(e)   -> tanh(x)
__device__ __forceinline__ float tanh2(float y) {
  return fmaf(-2.0f, __builtin_amdgcn_rcpf(1.0f + exp2_f(y)), 1.0f);
}

// Barrier that drains ONLY LDS ops (lgkmcnt). Global stores / prefetch loads
// stay in flight across it.
__device__ __forceinline__ void lds_barrier() {
  asm volatile("s_waitcnt lgkmcnt(0)" ::: "memory");
  __builtin_amdgcn_s_barrier();
  asm volatile("" ::: "memory");
}

// ---------------- prep: bf16 weight conversion + combined biases ----------------
// Weights/biases for sigmoid gates (i,f,o) scaled by -log2(e); tanh gate (g)
// scaled by +2*log2(e): cells then use raw v_exp_f32 (exp2) with no mul.
__global__ void k_prep(const float* __restrict__ wih1, const float* __restrict__ whh1,
                       const float* __restrict__ bih1, const float* __restrict__ bhh1,
                       const float* __restrict__ wih2, const float* __restrict__ whh2,
                       const float* __restrict__ bih2, const float* __restrict__ bhh2,
                       char* __restrict__ ws) {
  short* WHH1 = (short*)(ws + OFF_WHH1);
  short* WIH1 = (short*)(ws + OFF_WIH1);
  short* WIH2 = (short*)(ws + OFF_WIH2);
  short* WHH2 = (short*)(ws + OFF_WHH2);
  float* B1 = (float*)(ws + OFF_B1);
  float* B2 = (float*)(ws + OFF_B2);
  int idx = blockIdx.x * blockDim.x + threadIdx.x;
  int stride = gridDim.x * blockDim.x;
  const float SCI = -L2E, SCG = TWO_L2E;
  for (int i = idx; i < GG1 * DD; i += stride) {
    int g = (i >> 7) >> 7;                      // row/128 = gate
    float s = (g == 2) ? SCG : SCI;
    WIH1[i] = f2bf(wih1[i] * s); WHH1[i] = f2bf(whh1[i] * s);
  }
  for (int i = idx; i < GG2 * HH1; i += stride) {
    int g = (i >> 7) >> 6; float s = (g == 2) ? SCG : SCI;
    WIH2[i] = f2bf(wih2[i] * s);
  }
  for (int i = idx; i < GG2 * HH2; i += stride) {
    int g = (i >> 6) >> 6; float s = (g == 2) ? SCG : SCI;
    WHH2[i] = f2bf(whh2[i] * s);
  }
  for (int i = idx; i < GG1; i += stride) {
    float s = ((i >> 7) == 2) ? SCG : SCI;
    B1[i] = (bih1[i] + bhh1[i]) * s;
  }
  for (int i = idx; i < GG2; i += stride) {
    float s = ((i >> 6) == 2) ? SCG : SCI;
    B2[i] = (bih2[i] + bhh2[i]) * s;
  }
}

// ---------------- xcast: x fp32 -> bf16, 8 elems/thread ----------------
__global__ __launch_bounds__(256) void k_xcast(const float* __restrict__ x,
                                               short* __restrict__ xbf) {
  size_t i = ((size_t)blockIdx.x * 256 + threadIdx.x) * 8;
  float4 a = *(const float4*)&x[i];
  float4 b = *(const float4*)&x[i + 4];
  short8 o;
  o[0] = f2bf(a.x); o[1] = f2bf(a.y); o[2] = f2bf(a.z); o[3] = f2bf(a.w);
  o[4] = f2bf(b.x); o[5] = f2bf(b.y); o[6] = f2bf(b.z); o[7] = f2bf(b.w);
  *(short8*)&xbf[i] = o;
}

// ---------------- rec1f: fused input-proj + recurrence, layer 1 (R3 proven) ----
__global__ __launch_bounds__(512, 2) void k_rec1f(const char* __restrict__ ws,
                                                  short* __restrict__ h1s) {
  __shared__ short hbds[2][16 * 136];   // bf16 h double-buffer, rows 8..15 stay 0
  const short* WHH = (const short*)(ws + OFF_WHH1);
  const short* WIH = (const short*)(ws + OFF_WIH1);
  const short* XBF = (const short*)(ws + OFF_XBF);
  const float* B1 = (const float*)(ws + OFF_B1);
  const int lane = threadIdx.x & 63;
  const int wv = threadIdx.x >> 6;          // 0..7
  const int col = lane & 15, quad = lane >> 4;
  const int hc = wv * 16 + col;             // hidden col owned by this thread
  const int r0 = blockIdx.x * 8;

  short8 wh[4][4], wx[4][4];
#pragma unroll
  for (int gt = 0; gt < 4; ++gt)
#pragma unroll
    for (int kk = 0; kk < 4; ++kk) {
      wh[gt][kk] = *(const short8*)&WHH[(gt * 128 + hc) * HH1 + kk * 32 + quad * 8];
      wx[gt][kk] = *(const short8*)&WIH[(gt * 128 + hc) * DD + kk * 32 + quad * 8];
      PIN(wh[gt][kk]);
      PIN(wx[gt][kk]);
    }
  floatx4 BIASV[4];
#pragma unroll
  for (int gt = 0; gt < 4; ++gt) {
    float b = B1[gt * 128 + hc];
    BIASV[gt] = (floatx4){b, b, b, b};
    PIN(BIASV[gt]);
  }

  for (int i = threadIdx.x; i < 2 * 16 * 136; i += 512) ((short*)hbds)[i] = 0;

  const bool aload = (col < 8);
  const short* xbase = XBF + (size_t)(r0 + (col & 7)) * TT * DD;
  const short8 zz = {0, 0, 0, 0, 0, 0, 0, 0};
  short8 axA[4], axB[4];
  floatx4 accA[4], accB[4];

  // prologue: accA = bias + x_0*Wx ; axA = x_1 ; axB = 0
  {
    short8 ax0[4];
#pragma unroll
    for (int kk = 0; kk < 4; ++kk)
      ax0[kk] = aload ? *(const short8*)&xbase[kk * 32 + quad * 8] : zz;
#pragma unroll
    for (int gt = 0; gt < 4; ++gt)
      accA[gt] = __builtin_amdgcn_mfma_f32_16x16x32_bf16(ax0[0], wx[gt][0], BIASV[gt], 0, 0, 0);
#pragma unroll
    for (int kk = 1; kk < 4; ++kk)
#pragma unroll
      for (int gt = 0; gt < 4; ++gt)
        accA[gt] = __builtin_amdgcn_mfma_f32_16x16x32_bf16(ax0[kk], wx[gt][kk], accA[gt], 0, 0, 0);
  }
#pragma unroll
  for (int kk = 0; kk < 4; ++kk) {
    axA[kk] = aload ? *(const short8*)&xbase[DD + kk * 32 + quad * 8] : zz;
    axB[kk] = zz;
  }

  // rows covered after shfl rebalance: quad0->{0,1} quad1->{4,5} quad2->{2,3} quad3->{6,7}
  const int row0 = (quad & 1) * 4 + (quad >> 1) * 2;
  float c0 = 0.f, c1 = 0.f;
  __syncthreads();   // full barrier once (covers hbds zero-init)

  auto step = [&](int t, short* rbuf, short* wbuf, floatx4* A, floatx4* Bn,
                  short8* axC, short8* axP) {
    // prefetch x_{t+2} into the set consumed two steps from now
    if (aload && t + 2 < TT) {
#pragma unroll
      for (int kk = 0; kk < 4; ++kk)
        axP[kk] = *(const short8*)&xbase[(t + 2) * DD + kk * 32 + quad * 8];
    }
    // recurrence: A += h_t * Whh
    short8 ah[4];
#pragma unroll
    for (int kk = 0; kk < 4; ++kk)
      ah[kk] = *(const short8*)&rbuf[col * 136 + kk * 32 + quad * 8];
#pragma unroll
    for (int kk = 0; kk < 4; ++kk)
#pragma unroll
      for (int gt = 0; gt < 4; ++gt)
        A[gt] = __builtin_amdgcn_mfma_f32_16x16x32_bf16(ah[kk], wh[gt][kk], A[gt], 0, 0, 0);
    // pipelined input projection for t+1 (bias as MFMA C input, no movs)
#pragma unroll
    for (int gt = 0; gt < 4; ++gt)
      Bn[gt] = __builtin_amdgcn_mfma_f32_16x16x32_bf16(axC[0], wx[gt][0], BIASV[gt], 0, 0, 0);
#pragma unroll
    for (int kk = 1; kk < 4; ++kk)
#pragma unroll
      for (int gt = 0; gt < 4; ++gt)
        Bn[gt] = __builtin_amdgcn_mfma_f32_16x16x32_bf16(axC[kk], wx[gt][kk], Bn[gt], 0, 0, 0);

    // rebalance rows 2,3 / 6,7 onto quads 2,3 so all 64 lanes do 2 cells
    float g0[4], g1[4];
#pragma unroll
    for (int gt = 0; gt < 4; ++gt) {
      float v2 = __shfl_xor(A[gt][2], 32);
      float v3 = __shfl_xor(A[gt][3], 32);
      g0[gt] = (quad < 2) ? A[gt][0] : v2;
      g1[gt] = (quad < 2) ? A[gt][1] : v3;
    }
    {
      float i0 = sigm2(g0[0]), f0 = sigm2(g0[1]), gg0 = tanh2(g0[2]), o0 = sigm2(g0[3]);
      c0 = fmaf(f0, c0, i0 * gg0);
      float hA = o0 * tanh2(c0 * TWO_L2E);
      float i1 = sigm2(g1[0]), f1 = sigm2(g1[1]), gg1 = tanh2(g1[2]), o1 = sigm2(g1[3]);
      c1 = fmaf(f1, c1, i1 * gg1);
      float hB = o1 * tanh2(c1 * TWO_L2E);
      short ha = f2bf(hA), hbv = f2bf(hB);
      wbuf[(row0)     * 136 + hc] = ha;
      wbuf[(row0 + 1) * 136 + hc] = hbv;
      h1s[((size_t)(r0 + row0)     * TT + t) * HH1 + hc] = ha;
      h1s[((size_t)(r0 + row0 + 1) * TT + t) * HH1 + hc] = hbv;
    }
    lds_barrier();
  };

  for (int t = 0; t < TT; t += 2) {
    step(t,     &hbds[0][0], &hbds[1][0], accA, accB, axA, axB);
    step(t + 1, &hbds[1][0], &hbds[0][0], accB, accA, axB, axA);
  }
}

// ---------------- rec2w: layer 2, wave-specialized + dense head ----------------
// 8 rows/block, grid 256. Waves 4..7 = producers: compute xproj[t+1] =
// bias + h1[t+1]*Wih2 (R4-proven MFMA/loads) into double-buffered LDS xacc,
// laid out [n][row] so floatx4 (rows quad*4+r) moves as one b128. Waves 0..3
// = consumers: recurrence MFMA with C operand read straight from xacc (b128),
// register cell with the rec1f-proven shfl rebalance. 1 lgkm barrier/step.
__global__ __launch_bounds__(512, 2) void k_rec2w(const char* __restrict__ ws,
                                                  const short* __restrict__ h1s,
                                                  const float* __restrict__ wd,
                                                  const float* __restrict__ bd,
                                                  float* __restrict__ out) {
  __shared__ __align__(16) float xacc[2][256 * 20];  // [buf][n*20 + row], 40KB
  __shared__ short hbuf[2][16 * 72];                 // h2 dbuf, rows 8..15 stay 0
  __shared__ float h2f[8 * HH2];                     // final fp32 h2
  const int lane = threadIdx.x & 63;
  const int wv = threadIdx.x >> 6;          // 0..7
  const int col = lane & 15, quad = lane >> 4;
  const int r0 = blockIdx.x * 8;

  for (int i = threadIdx.x; i < 2 * 256 * 20; i += 512) ((float*)xacc)[i] = 0.f;
  for (int i = threadIdx.x; i < 2 * 16 * 72; i += 512) ((short*)hbuf)[i] = 0;

  if (wv >= 4) {
    // ========== producer waves: input projection, one step ahead ==========
    const short* WIH = (const short*)(ws + OFF_WIH2);
    const float* B2 = (const float*)(ws + OFF_B2);
    const int hcp = (wv - 4) * 16 + col;    // hidden col 0..63
    short8 wx[4][4];
#pragma unroll
    for (int gt = 0; gt < 4; ++gt)
#pragma unroll
      for (int kk = 0; kk < 4; ++kk) {
        wx[gt][kk] = *(const short8*)&WIH[(gt * 64 + hcp) * HH1 + kk * 32 + quad * 8];
        PIN(wx[gt][kk]);
      }
    floatx4 BIASV[4];
#pragma unroll
    for (int gt = 0; gt < 4; ++gt) {
      float b = B2[gt * 64 + hcp];
      BIASV[gt] = (floatx4){b, b, b, b};
      PIN(BIASV[gt]);
    }
    const bool aload = (col < 8);
    const short* h1base = h1s + (size_t)(r0 + (col & 7)) * TT * HH1;
    const short8 zz = {0, 0, 0, 0, 0, 0, 0, 0};
    short8 axA[4], axB[4];

    // prologue: xacc[0] = bias + h1[0]*Wx ; axA = h1[1]
    {
      short8 ax0[4];
#pragma unroll
      for (int kk = 0; kk < 4; ++kk)
        ax0[kk] = aload ? *(const short8*)&h1base[kk * 32 + quad * 8] : zz;
      floatx4 Bn[4];
#pragma unroll
      for (int gt = 0; gt < 4; ++gt)
        Bn[gt] = __builtin_amdgcn_mfma_f32_16x16x32_bf16(ax0[0], wx[gt][0], BIASV[gt], 0, 0, 0);
#pragma unroll
      for (int kk = 1; kk < 4; ++kk)
#pragma unroll
        for (int gt = 0; gt < 4; ++gt)
          Bn[gt] = __builtin_amdgcn_mfma_f32_16x16x32_bf16(ax0[kk], wx[gt][kk], Bn[gt], 0, 0, 0);
      if (quad < 2) {                        // rows 0..7 real
#pragma unroll
        for (int gt = 0; gt < 4; ++gt)
          *(floatx4*)&xacc[0][(gt * 64 + hcp) * 20 + quad * 4] = Bn[gt];
      }
    }
#pragma unroll
    for (int kk = 0; kk < 4; ++kk) {
      axA[kk] = aload ? *(const short8*)&h1base[HH1 + kk * 32 + quad * 8] : zz;
      axB[kk] = zz;
    }
    __syncthreads();   // covers LDS zero-init + xacc[0]

    auto pstep = [&](int t, short8* axC, short8* axP) {
      if (t + 1 < TT) {
        floatx4 Bn[4];
#pragma unroll
        for (int gt = 0; gt < 4; ++gt)
          Bn[gt] = __builtin_amdgcn_mfma_f32_16x16x32_bf16(axC[0], wx[gt][0], BIASV[gt], 0, 0, 0);
#pragma unroll
        for (int kk = 1; kk < 4; ++kk)
#pragma unroll
          for (int gt = 0; gt < 4; ++gt)
            Bn[gt] = __builtin_amdgcn_mfma_f32_16x16x32_bf16(axC[kk], wx[gt][kk], Bn[gt], 0, 0, 0);
        if (quad < 2) {
#pragma unroll
          for (int gt = 0; gt < 4; ++gt)
            *(floatx4*)&xacc[(t + 1) & 1][(gt * 64 + hcp) * 20 + quad * 4] = Bn[gt];
        }
      }
      if (aload && t + 2 < TT) {
#pragma unroll
        for (int kk = 0; kk < 4; ++kk)
          axP[kk] = *(const short8*)&h1base[(t + 2) * HH1 + kk * 32 + quad * 8];
      }
      lds_barrier();
    };

    for (int t = 0; t < TT; t += 2) {
      pstep(t, axA, axB);
      pstep(t + 1, axB, axA);
    }

  } else {
    // ========== consumer waves: recurrence + register cell ==========
    const short* WHH = (const short*)(ws + OFF_WHH2);
    const int hc = wv * 16 + col;           // hidden col 0..63
    short8 wh[4][2];
#pragma unroll
    for (int gt = 0; gt < 4; ++gt)
#pragma unroll
      for (int kk = 0; kk < 2; ++kk) {
        wh[gt][kk] = *(const short8*)&WHH[(gt * 64 + hc) * HH2 + kk * 32 + quad * 8];
        PIN(wh[gt][kk]);
      }
    const int row0 = (quad & 1) * 4 + (quad >> 1) * 2;  // rec1f-proven rebalance
    float c0 = 0.f, c1 = 0.f;
    __syncthreads();   // matches producer prologue barrier

    auto cstep = [&](int t) {
      const int cur = t & 1;
      // recurrence A-operand: h2[t-1] (rows 8..15 of hbuf stay 0)
      short8 ah[2];
#pragma unroll
      for (int kk = 0; kk < 2; ++kk)
        ah[kk] = *(const short8*)&hbuf[cur][col * 72 + kk * 32 + quad * 8];
      // C operand = bias + h1[t]*Wih2, straight from xacc (rows 8..15 are 0)
      floatx4 A[4];
#pragma unroll
      for (int gt = 0; gt < 4; ++gt)
        A[gt] = *(const floatx4*)&xacc[cur][(gt * 64 + hc) * 20 + quad * 4];
#pragma unroll
      for (int kk = 0; kk < 2; ++kk)
#pragma unroll
        for (int gt = 0; gt < 4; ++gt)
          A[gt] = __builtin_amdgcn_mfma_f32_16x16x32_bf16(ah[kk], wh[gt][kk], A[gt], 0, 0, 0);

      float g0[4], g1[4];
#pragma unroll
      for (int gt = 0; gt < 4; ++gt) {
        float v2 = __shfl_xor(A[gt][2], 32);
        float v3 = __shfl_xor(A[gt][3], 32);
        g0[gt] = (quad < 2) ? A[gt][0] : v2;
        g1[gt] = (quad < 2) ? A[gt][1] : v3;
      }
      float i0 = sigm2(g0[0]), f0 = sigm2(g0[1]), gg0 = tanh2(g0[2]), o0 = sigm2(g0[3]);
      c0 = fmaf(f0, c0, i0 * gg0);
      float hA = o0 * tanh2(c0 * TWO_L2E);
      float i1 = sigm2(g1[0]), f1 = sigm2(g1[1]), gg1 = tanh2(g1[2]), o1 = sigm2(g1[3]);
      c1 = fmaf(f1, c1, i1 * gg1);
      float hB = o1 * tanh2(c1 * TWO_L2E);
      hbuf[cur ^ 1][(row0)     * 72 + hc] = f2bf(hA);
      hbuf[cur ^ 1][(row0 + 1) * 72 + hc] = f2bf(hB);
      if (t == TT - 1) {
        h2f[(row0)     * HH2 + hc] = hA;
        h2f[(row0 + 1) * HH2 + hc] = hB;
      }
      lds_barrier();
    };

    for (int t = 0; t < TT; ++t) cstep(t);
  }

  __syncthreads();   // h2f visible to all 8 waves

  // dense head (fp32): 8 rows x 64 outs = 512 threads, 1 each
  {
    const int o = threadIdx.x & 63;
    const int r = threadIdx.x >> 6;   // 0..7
    float acc = bd[o];
    for (int k = 0; k < HH2; ++k)
      acc = fmaf(h2f[r * HH2 + k], wd[o * HH2 + k], acc);
    out[(size_t)(r0 + r) * OO + o] = fmaxf(acc, 0.f);
  }
}

extern "C" void kernel_launch(void* const* d_in, const int* in_sizes, int n_in,
                              void* d_out, int out_size, void* d_ws, size_t ws_size,
                              hipStream_t stream) {
  const float* x       = (const float*)d_in[0];
  const float* w_ih1   = (const float*)d_in[1];
  const float* w_hh1   = (const float*)d_in[2];
  const float* b_ih1   = (const float*)d_in[3];
  const float* b_hh1   = (const float*)d_in[4];
  const float* w_ih2   = (const float*)d_in[5];
  const float* w_hh2   = (const float*)d_in[6];
  const float* b_ih2   = (const float*)d_in[7];
  const float* b_hh2   = (const float*)d_in[8];
  const float* w_dense = (const float*)d_in[9];
  const float* b_dense = (const float*)d_in[10];
  char* ws = (char*)d_ws;
  short* xbf = (short*)(ws + OFF_XBF);
  short* h1s = (short*)(ws + OFF_H1S);
  float* out = (float*)d_out;

  hipLaunchKernelGGL(k_prep, dim3(256), dim3(256), 0, stream,
                     w_ih1, w_hh1, b_ih1, b_hh1, w_ih2, w_hh2, b_ih2, b_hh2, ws);
  hipLaunchKernelGGL(k_xcast, dim3((BB * TT * DD) / (256 * 8)), dim3(256), 0, stream, x, xbf);
  hipLaunchKernelGGL(k_rec1f, dim3(BB / 8), dim3(512), 0, stream, ws, h1s);
  hipLaunchKernelGGL(k_rec2w, dim3(BB / 8), dim3(512), 0, stream, ws, h1s, w_dense, b_dense, out);
}

// Round 8
// 362.351 us; speedup vs baseline: 6.8790x; 1.1435x over previous
//
#include <hip/hip_runtime.h>
#include <hip/hip_bf16.h>

#define BB  2048
#define TT  128
#define DD  128
#define HH1 128
#define GG1 512
#define HH2 64
#define GG2 256
#define OO  64

typedef __attribute__((ext_vector_type(8))) short  short8;
typedef __attribute__((ext_vector_type(4))) float  floatx4;

// Pin a value into VGPRs: opaque asm makes rematerializing the load illegal.
#define PIN(x) asm volatile("" : "+v"(x))

// ws byte offsets
#define OFF_WHH1 0            // bf16 [512][128]  (exp2-prescaled)
#define OFF_WIH1 131072       // bf16 [512][128]  (exp2-prescaled)
#define OFF_WIH2 262144       // bf16 [256][128]  (exp2-prescaled)
#define OFF_WHH2 327680       // bf16 [256][64]   (exp2-prescaled)
#define OFF_B1   360448       // f32 [512]  (b_ih1+b_hh1)*scale
#define OFF_B2   362496       // f32 [256]  (b_ih2+b_hh2)*scale
#define OFF_H1S  67633152     // bf16 [2048][128][128]  layer-1 hidden seq

#define L2E      1.44269504088896340736f
#define TWO_L2E  2.88539008177792681472f

__device__ __forceinline__ short f2bf(float f) {
  unsigned u = __float_as_uint(f);
  unsigned r = (u + 0x7FFFu + ((u >> 16) & 1u)) >> 16;
  return (short)r;
}
__device__ __forceinline__ float exp2_f(float x) {
  float r; asm("v_exp_f32 %0, %1" : "=v"(r) : "v"(x)); return r;
}
// y is pre-scaled: y = -x*log2(e)   -> sigmoid(x)
__device__ __forceinline__ float sigm2(float y) {
  return __builtin_amdgcn_rcpf(1.0f + exp2_f(y));
}
// y is pre-scaled: y = 2x*log2(e)   -> tanh(x)
__device__ __forceinline__ float tanh2(float y) {
  return fmaf(-2.0f, __builtin_amdgcn_rcpf(1.0f + exp2_f(y)), 1.0f);
}
// pack 2 f32 -> 2 bf16 (RNE, proven bit-equal to f2bf in R3/R4 runs)
__device__ __forceinline__ unsigned cvtpk(float a, float b) {
  unsigned r;
  asm("v_cvt_pk_bf16_f32 %0, %1, %2" : "=v"(r) : "v"(a), "v"(b));
  return r;
}

// Barrier that drains ONLY LDS ops (lgkmcnt). Global stores / prefetch loads
// stay in flight across it.
__device__ __forceinline__ void lds_barrier() {
  asm volatile("s_waitcnt lgkmcnt(0)" ::: "memory");
  __builtin_amdgcn_s_barrier();
  asm volatile("" ::: "memory");
}

// ---------------- prep: bf16 weight conversion + combined biases ----------------
// Weights/biases for sigmoid gates (i,f,o) scaled by -log2(e); tanh gate (g)
// scaled by +2*log2(e): cells then use raw v_exp_f32 (exp2) with no mul.
__global__ void k_prep(const float* __restrict__ wih1, const float* __restrict__ whh1,
                       const float* __restrict__ bih1, const float* __restrict__ bhh1,
                       const float* __restrict__ wih2, const float* __restrict__ whh2,
                       const float* __restrict__ bih2, const float* __restrict__ bhh2,
                       char* __restrict__ ws) {
  short* WHH1 = (short*)(ws + OFF_WHH1);
  short* WIH1 = (short*)(ws + OFF_WIH1);
  short* WIH2 = (short*)(ws + OFF_WIH2);
  short* WHH2 = (short*)(ws + OFF_WHH2);
  float* B1 = (float*)(ws + OFF_B1);
  float* B2 = (float*)(ws + OFF_B2);
  int idx = blockIdx.x * blockDim.x + threadIdx.x;
  int stride = gridDim.x * blockDim.x;
  const float SCI = -L2E, SCG = TWO_L2E;
  for (int i = idx; i < GG1 * DD; i += stride) {
    int g = (i >> 7) >> 7;                      // row/128 = gate
    float s = (g == 2) ? SCG : SCI;
    WIH1[i] = f2bf(wih1[i] * s); WHH1[i] = f2bf(whh1[i] * s);
  }
  for (int i = idx; i < GG2 * HH1; i += stride) {
    int g = (i >> 7) >> 6; float s = (g == 2) ? SCG : SCI;
    WIH2[i] = f2bf(wih2[i] * s);
  }
  for (int i = idx; i < GG2 * HH2; i += stride) {
    int g = (i >> 6) >> 6; float s = (g == 2) ? SCG : SCI;
    WHH2[i] = f2bf(whh2[i] * s);
  }
  for (int i = idx; i < GG1; i += stride) {
    float s = ((i >> 7) == 2) ? SCG : SCI;
    B1[i] = (bih1[i] + bhh1[i]) * s;
  }
  for (int i = idx; i < GG2; i += stride) {
    float s = ((i >> 6) == 2) ? SCG : SCI;
    B2[i] = (bih2[i] + bhh2[i]) * s;
  }
}

// ---------------- rec1f: layer 1 with in-kernel x streaming (no xcast) ---------
// R3-proven 8-row recurrence structure. New: x is read as f32 directly and
// converted through a 4-slot LDS ring with full-step latency slack:
//   step t: ds_write x[t+4] (cvt of float2 loaded at t-1) -> slot t&3
//           issue float2 load of x[t+5]
//           ds_read ax x[t+2] from slot (t+2)&3  (conflict-free 136-stride)
// Slot reuse is >=2 barriers apart; prologue fills slots 0..3 (x[0..3]).
__global__ __launch_bounds__(512, 2) void k_rec1f(const char* __restrict__ ws,
                                                  const float* __restrict__ x,
                                                  short* __restrict__ h1s) {
  __shared__ short hbds[2][16 * 136];   // bf16 h double-buffer, rows 8..15 stay 0
  __shared__ short ring[4][8 * 136];    // bf16 x ring, padded stride
  const short* WHH = (const short*)(ws + OFF_WHH1);
  const short* WIH = (const short*)(ws + OFF_WIH1);
  const float* B1 = (const float*)(ws + OFF_B1);
  const int lane = threadIdx.x & 63;
  const int wv = threadIdx.x >> 6;          // 0..7
  const int col = lane & 15, quad = lane >> 4;
  const int hc = wv * 16 + col;             // hidden col owned by this thread
  const int r0 = blockIdx.x * 8;

  short8 wh[4][4], wx[4][4];
#pragma unroll
  for (int gt = 0; gt < 4; ++gt)
#pragma unroll
    for (int kk = 0; kk < 4; ++kk) {
      wh[gt][kk] = *(const short8*)&WHH[(gt * 128 + hc) * HH1 + kk * 32 + quad * 8];
      wx[gt][kk] = *(const short8*)&WIH[(gt * 128 + hc) * DD + kk * 32 + quad * 8];
      PIN(wh[gt][kk]);
      PIN(wx[gt][kk]);
    }
  floatx4 BIASV[4];
#pragma unroll
  for (int gt = 0; gt < 4; ++gt) {
    float b = B1[gt * 128 + hc];
    BIASV[gt] = (floatx4){b, b, b, b};
    PIN(BIASV[gt]);
  }

  for (int i = threadIdx.x; i < 2 * 16 * 136; i += 512) ((short*)hbds)[i] = 0;

  // x streaming geometry: thread -> (row rrow, col pair rcp)
  const int rrow = threadIdx.x >> 6;        // 0..7 (= wv)
  const int rcp  = threadIdx.x & 63;        // 0..63
  const float* xsrc = x + (size_t)(r0 + rrow) * TT * DD + rcp * 2;

  // prologue: fill ring slots 0..3 with x[0..3]; stage x[4] in regs
#pragma unroll
  for (int tt = 0; tt < 4; ++tt) {
    float2 f = *(const float2*)&xsrc[tt * DD];
    *(unsigned*)&ring[tt][rrow * 136 + rcp * 2] = cvtpk(f.x, f.y);
  }
  float2 pfA = *(const float2*)&xsrc[4 * DD];
  float2 pfB = pfA;
  __syncthreads();   // ring[0..3] + hbds zeros visible

  const bool aload = (col < 8);
  const short8 zz = {0, 0, 0, 0, 0, 0, 0, 0};
  short8 axA[4], axB[4];
  floatx4 accA[4], accB[4];

  // accA = bias + x_0*Wx (x_0 from ring[0]); axA = x_1 (ring[1])
  {
    short8 ax0[4];
#pragma unroll
    for (int kk = 0; kk < 4; ++kk)
      ax0[kk] = aload ? *(const short8*)&ring[0][col * 136 + kk * 32 + quad * 8] : zz;
#pragma unroll
    for (int gt = 0; gt < 4; ++gt)
      accA[gt] = __builtin_amdgcn_mfma_f32_16x16x32_bf16(ax0[0], wx[gt][0], BIASV[gt], 0, 0, 0);
#pragma unroll
    for (int kk = 1; kk < 4; ++kk)
#pragma unroll
      for (int gt = 0; gt < 4; ++gt)
        accA[gt] = __builtin_amdgcn_mfma_f32_16x16x32_bf16(ax0[kk], wx[gt][kk], accA[gt], 0, 0, 0);
  }
#pragma unroll
  for (int kk = 0; kk < 4; ++kk) {
    axA[kk] = aload ? *(const short8*)&ring[1][col * 136 + kk * 32 + quad * 8] : zz;
    axB[kk] = zz;
  }
  __syncthreads();   // protect prologue ring reads from step-0 ring write

  // rows covered after shfl rebalance: quad0->{0,1} quad1->{4,5} quad2->{2,3} quad3->{6,7}
  const int row0 = (quad & 1) * 4 + (quad >> 1) * 2;
  float c0 = 0.f, c1 = 0.f;

  auto step = [&](int t, short* rbuf, short* wbuf, floatx4* A, floatx4* Bn,
                  short8* axC, short8* axP, float2& pfC, float2& pfP) {
    // stream x: write x[t+4] (cvt of pfC) into slot t&3; load x[t+5]
    if (t + 4 < TT)
      *(unsigned*)&ring[t & 3][rrow * 136 + rcp * 2] = cvtpk(pfC.x, pfC.y);
    if (t + 5 < TT)
      pfP = *(const float2*)&xsrc[(t + 5) * DD];
    // ax prefetch for step t+1's xproj: x[t+2] from slot (t+2)&3
    if (aload && t + 2 < TT) {
#pragma unroll
      for (int kk = 0; kk < 4; ++kk)
        axP[kk] = *(const short8*)&ring[(t + 2) & 3][col * 136 + kk * 32 + quad * 8];
    }
    // recurrence: A += h_t * Whh
    short8 ah[4];
#pragma unroll
    for (int kk = 0; kk < 4; ++kk)
      ah[kk] = *(const short8*)&rbuf[col * 136 + kk * 32 + quad * 8];
#pragma unroll
    for (int kk = 0; kk < 4; ++kk)
#pragma unroll
      for (int gt = 0; gt < 4; ++gt)
        A[gt] = __builtin_amdgcn_mfma_f32_16x16x32_bf16(ah[kk], wh[gt][kk], A[gt], 0, 0, 0);
    // pipelined input projection for t+1 (bias as MFMA C input)
#pragma unroll
    for (int gt = 0; gt < 4; ++gt)
      Bn[gt] = __builtin_amdgcn_mfma_f32_16x16x32_bf16(axC[0], wx[gt][0], BIASV[gt], 0, 0, 0);
#pragma unroll
    for (int kk = 1; kk < 4; ++kk)
#pragma unroll
      for (int gt = 0; gt < 4; ++gt)
        Bn[gt] = __builtin_amdgcn_mfma_f32_16x16x32_bf16(axC[kk], wx[gt][kk], Bn[gt], 0, 0, 0);

    // rebalance rows 2,3 / 6,7 onto quads 2,3 so all 64 lanes do 2 cells
    float g0[4], g1[4];
#pragma unroll
    for (int gt = 0; gt < 4; ++gt) {
      float v2 = __shfl_xor(A[gt][2], 32);
      float v3 = __shfl_xor(A[gt][3], 32);
      g0[gt] = (quad < 2) ? A[gt][0] : v2;
      g1[gt] = (quad < 2) ? A[gt][1] : v3;
    }
    {
      float i0 = sigm2(g0[0]), f0 = sigm2(g0[1]), gg0 = tanh2(g0[2]), o0 = sigm2(g0[3]);
      c0 = fmaf(f0, c0, i0 * gg0);
      float hA = o0 * tanh2(c0 * TWO_L2E);
      float i1 = sigm2(g1[0]), f1 = sigm2(g1[1]), gg1 = tanh2(g1[2]), o1 = sigm2(g1[3]);
      c1 = fmaf(f1, c1, i1 * gg1);
      float hB = o1 * tanh2(c1 * TWO_L2E);
      short ha = f2bf(hA), hbv = f2bf(hB);
      wbuf[(row0)     * 136 + hc] = ha;
      wbuf[(row0 + 1) * 136 + hc] = hbv;
      h1s[((size_t)(r0 + row0)     * TT + t) * HH1 + hc] = ha;
      h1s[((size_t)(r0 + row0 + 1) * TT + t) * HH1 + hc] = hbv;
    }
    lds_barrier();
  };

  for (int t = 0; t < TT; t += 2) {
    step(t,     &hbds[0][0], &hbds[1][0], accA, accB, axA, axB, pfA, pfB);
    step(t + 1, &hbds[1][0], &hbds[0][0], accB, accA, axB, axA, pfB, pfA);
  }
}

// ---------------- rec2w: layer 2, wave-specialized + dense head (R7 proven) ----
__global__ __launch_bounds__(512, 2) void k_rec2w(const char* __restrict__ ws,
                                                  const short* __restrict__ h1s,
                                                  const float* __restrict__ wd,
                                                  const float* __restrict__ bd,
                                                  float* __restrict__ out) {
  __shared__ __align__(16) float xacc[2][256 * 20];  // [buf][n*20 + row], 40KB
  __shared__ short hbuf[2][16 * 72];                 // h2 dbuf, rows 8..15 stay 0
  __shared__ float h2f[8 * HH2];                     // final fp32 h2
  const int lane = threadIdx.x & 63;
  const int wv = threadIdx.x >> 6;          // 0..7
  const int col = lane & 15, quad = lane >> 4;
  const int r0 = blockIdx.x * 8;

  for (int i = threadIdx.x; i < 2 * 256 * 20; i += 512) ((float*)xacc)[i] = 0.f;
  for (int i = threadIdx.x; i < 2 * 16 * 72; i += 512) ((short*)hbuf)[i] = 0;

  if (wv >= 4) {
    // ========== producer waves: input projection, one step ahead ==========
    const short* WIH = (const short*)(ws + OFF_WIH2);
    const float* B2 = (const float*)(ws + OFF_B2);
    const int hcp = (wv - 4) * 16 + col;    // hidden col 0..63
    short8 wx[4][4];
#pragma unroll
    for (int gt = 0; gt < 4; ++gt)
#pragma unroll
      for (int kk = 0; kk < 4; ++kk) {
        wx[gt][kk] = *(const short8*)&WIH[(gt * 64 + hcp) * HH1 + kk * 32 + quad * 8];
        PIN(wx[gt][kk]);
      }
    floatx4 BIASV[4];
#pragma unroll
    for (int gt = 0; gt < 4; ++gt) {
      float b = B2[gt * 64 + hcp];
      BIASV[gt] = (floatx4){b, b, b, b};
      PIN(BIASV[gt]);
    }
    const bool aload = (col < 8);
    const short* h1base = h1s + (size_t)(r0 + (col & 7)) * TT * HH1;
    const short8 zz = {0, 0, 0, 0, 0, 0, 0, 0};
    short8 axA[4], axB[4];

    // prologue: xacc[0] = bias + h1[0]*Wx ; axA = h1[1]
    {
      short8 ax0[4];
#pragma unroll
      for (int kk = 0; kk < 4; ++kk)
        ax0[kk] = aload ? *(const short8*)&h1base[kk * 32 + quad * 8] : zz;
      floatx4 Bn[4];
#pragma unroll
      for (int gt = 0; gt < 4; ++gt)
        Bn[gt] = __builtin_amdgcn_mfma_f32_16x16x32_bf16(ax0[0], wx[gt][0], BIASV[gt], 0, 0, 0);
#pragma unroll
      for (int kk = 1; kk < 4; ++kk)
#pragma unroll
        for (int gt = 0; gt < 4; ++gt)
          Bn[gt] = __builtin_amdgcn_mfma_f32_16x16x32_bf16(ax0[kk], wx[gt][kk], Bn[gt], 0, 0, 0);
      if (quad < 2) {                        // rows 0..7 real
#pragma unroll
        for (int gt = 0; gt < 4; ++gt)
          *(floatx4*)&xacc[0][(gt * 64 + hcp) * 20 + quad * 4] = Bn[gt];
      }
    }
#pragma unroll
    for (int kk = 0; kk < 4; ++kk) {
      axA[kk] = aload ? *(const short8*)&h1base[HH1 + kk * 32 + quad * 8] : zz;
      axB[kk] = zz;
    }
    __syncthreads();   // covers LDS zero-init + xacc[0]

    auto pstep = [&](int t, short8* axC, short8* axP) {
      if (t + 1 < TT) {
        floatx4 Bn[4];
#pragma unroll
        for (int gt = 0; gt < 4; ++gt)
          Bn[gt] = __builtin_amdgcn_mfma_f32_16x16x32_bf16(axC[0], wx[gt][0], BIASV[gt], 0, 0, 0);
#pragma unroll
        for (int kk = 1; kk < 4; ++kk)
#pragma unroll
          for (int gt = 0; gt < 4; ++gt)
            Bn[gt] = __builtin_amdgcn_mfma_f32_16x16x32_bf16(axC[kk], wx[gt][kk], Bn[gt], 0, 0, 0);
        if (quad < 2) {
#pragma unroll
          for (int gt = 0; gt < 4; ++gt)
            *(floatx4*)&xacc[(t + 1) & 1][(gt * 64 + hcp) * 20 + quad * 4] = Bn[gt];
        }
      }
      if (aload && t + 2 < TT) {
#pragma unroll
        for (int kk = 0; kk < 4; ++kk)
          axP[kk] = *(const short8*)&h1base[(t + 2) * HH1 + kk * 32 + quad * 8];
      }
      lds_barrier();
    };

    for (int t = 0; t < TT; t += 2) {
      pstep(t, axA, axB);
      pstep(t + 1, axB, axA);
    }

  } else {
    // ========== consumer waves: recurrence + register cell ==========
    const short* WHH = (const short*)(ws + OFF_WHH2);
    const int hc = wv * 16 + col;           // hidden col 0..63
    short8 wh[4][2];
#pragma unroll
    for (int gt = 0; gt < 4; ++gt)
#pragma unroll
      for (int kk = 0; kk < 2; ++kk) {
        wh[gt][kk] = *(const short8*)&WHH[(gt * 64 + hc) * HH2 + kk * 32 + quad * 8];
        PIN(wh[gt][kk]);
      }
    const int row0 = (quad & 1) * 4 + (quad >> 1) * 2;  // rec1f-proven rebalance
    float c0 = 0.f, c1 = 0.f;
    __syncthreads();   // matches producer prologue barrier

    auto cstep = [&](int t) {
      const int cur = t & 1;
      // recurrence A-operand: h2[t-1] (rows 8..15 of hbuf stay 0)
      short8 ah[2];
#pragma unroll
      for (int kk = 0; kk < 2; ++kk)
        ah[kk] = *(const short8*)&hbuf[cur][col * 72 + kk * 32 + quad * 8];
      // C operand = bias + h1[t]*Wih2, straight from xacc (rows 8..15 are 0)
      floatx4 A[4];
#pragma unroll
      for (int gt = 0; gt < 4; ++gt)
        A[gt] = *(const floatx4*)&xacc[cur][(gt * 64 + hc) * 20 + quad * 4];
#pragma unroll
      for (int kk = 0; kk < 2; ++kk)
#pragma unroll
        for (int gt = 0; gt < 4; ++gt)
          A[gt] = __builtin_amdgcn_mfma_f32_16x16x32_bf16(ah[kk], wh[gt][kk], A[gt], 0, 0, 0);

      float g0[4], g1[4];
#pragma unroll
      for (int gt = 0; gt < 4; ++gt) {
        float v2 = __shfl_xor(A[gt][2], 32);
        float v3 = __shfl_xor(A[gt][3], 32);
        g0[gt] = (quad < 2) ? A[gt][0] : v2;
        g1[gt] = (quad < 2) ? A[gt][1] : v3;
      }
      float i0 = sigm2(g0[0]), f0 = sigm2(g0[1]), gg0 = tanh2(g0[2]), o0 = sigm2(g0[3]);
      c0 = fmaf(f0, c0, i0 * gg0);
      float hA = o0 * tanh2(c0 * TWO_L2E);
      float i1 = sigm2(g1[0]), f1 = sigm2(g1[1]), gg1 = tanh2(g1[2]), o1 = sigm2(g1[3]);
      c1 = fmaf(f1, c1, i1 * gg1);
      float hB = o1 * tanh2(c1 * TWO_L2E);
      hbuf[cur ^ 1][(row0)     * 72 + hc] = f2bf(hA);
      hbuf[cur ^ 1][(row0 + 1) * 72 + hc] = f2bf(hB);
      if (t == TT - 1) {
        h2f[(row0)     * HH2 + hc] = hA;
        h2f[(row0 + 1) * HH2 + hc] = hB;
      }
      lds_barrier();
    };

    for (int t = 0; t < TT; ++t) cstep(t);
  }

  __syncthreads();   // h2f visible to all 8 waves

  // dense head (fp32): 8 rows x 64 outs = 512 threads, 1 each
  {
    const int o = threadIdx.x & 63;
    const int r = threadIdx.x >> 6;   // 0..7
    float acc = bd[o];
    for (int k = 0; k < HH2; ++k)
      acc = fmaf(h2f[r * HH2 + k], wd[o * HH2 + k], acc);
    out[(size_t)(r0 + r) * OO + o] = fmaxf(acc, 0.f);
  }
}

extern "C" void kernel_launch(void* const* d_in, const int* in_sizes, int n_in,
                              void* d_out, int out_size, void* d_ws, size_t ws_size,
                              hipStream_t stream) {
  const float* x       = (const float*)d_in[0];
  const float* w_ih1   = (const float*)d_in[1];
  const float* w_hh1   = (const float*)d_in[2];
  const float* b_ih1   = (const float*)d_in[3];
  const float* b_hh1   = (const float*)d_in[4];
  const float* w_ih2   = (const float*)d_in[5];
  const float* w_hh2   = (const float*)d_in[6];
  const float* b_ih2   = (const float*)d_in[7];
  const float* b_hh2   = (const float*)d_in[8];
  const float* w_dense = (const float*)d_in[9];
  const float* b_dense = (const float*)d_in[10];
  char* ws = (char*)d_ws;
  short* h1s = (short*)(ws + OFF_H1S);
  float* out = (float*)d_out;

  hipLaunchKernelGGL(k_prep, dim3(256), dim3(256), 0, stream,
                     w_ih1, w_hh1, b_ih1, b_hh1, w_ih2, w_hh2, b_ih2, b_hh2, ws);
  hipLaunchKernelGGL(k_rec1f, dim3(BB / 8), dim3(512), 0, stream, ws, x, h1s);
  hipLaunchKernelGGL(k_rec2w, dim3(BB / 8), dim3(512), 0, stream, ws, h1s, w_dense, b_dense, out);
}